// Round 16
// baseline (180.873 us; speedup 1.0000x reference)
//
#include <hip/hip_runtime.h>
#include <hip/hip_fp16.h>
#include <math.h>

#define GR 128            // grid resolution
#define GB 64             // bricks per axis (2x2x2-voxel bricks)
#define NCH 28            // real channels (1 density + 27 SH)

typedef float fvec4 __attribute__((ext_vector_type(4)));

// ---------------------------------------------------------------------------
// 16-byte voxel (R8-proven), stored in 2x2x2-voxel bricks so one brick =
// 8 voxels x 16 B = exactly one 128 B cache line.
//   brick(bx,by,bz) at ((bz*GB+by)*GB+bx)*8 ; voxel offset (z&1)<<2|(y&1)<<1|(x&1)
//   dword0: SH nibbles c0..c7, dword1: c8..c15, dword2: c16..c23
//   dword3: [3:0]=c24 [7:4]=c25 [11:8]=c26 [15:12]=e, [31:16]=density fp16
// SH coef value = (n - 8) * 2^(e-14)
// ---------------------------------------------------------------------------

__device__ __forceinline__ float sigmoidf_(float x) {
    return 1.0f / (1.0f + expf(-x));
}
__device__ __forceinline__ __half2 u2h2(unsigned int u) {
    return *reinterpret_cast<__half2*>(&u);
}
__device__ __forceinline__ int brick_addr(int x, int y, int z) {
    int b = ((z >> 1) * GB + (y >> 1)) * GB + (x >> 1);
    return b * 8 + ((z & 1) << 2) + ((y & 1) << 1) + (x & 1);
}

// encode one voxel's 27 SH + density into two uint4 (R8-proven format)
__device__ __forceinline__ void enc_voxel(const float* sv, float dv,
                                          uint4& lo, uint4& hi) {
    float mp = 0.0f, mn = 0.0f;
#pragma unroll
    for (int q = 0; q < 27; ++q) {
        float xq = sv[q];
        mp = fmaxf(mp, xq);
        mn = fmaxf(mn, -xq);
    }
    float tq = fmaxf(fmaxf(mp * (1.0f / 7.0f), mn * 0.125f), 7.5e-9f);
    int ex = (int)((__float_as_uint(tq) >> 23) & 0xFFu) - 126;
    int e = min(max(ex + 14, 0), 15);
    float invf = __uint_as_float((unsigned int)(141 - e) << 23);  // 2^(14-e)

    unsigned int w[4];
#pragma unroll
    for (int d = 0; d < 3; ++d) {
        unsigned int acc = 0;
#pragma unroll
        for (int b = 0; b < 8; ++b) {
            int n = (int)rintf(sv[8 * d + b] * invf) + 8;
            n = min(max(n, 0), 15);
            acc |= (unsigned int)n << (4 * b);
        }
        w[d] = acc;
    }
    int n24 = min(max((int)rintf(sv[24] * invf) + 8, 0), 15);
    int n25 = min(max((int)rintf(sv[25] * invf) + 8, 0), 15);
    int n26 = min(max((int)rintf(sv[26] * invf) + 8, 0), 15);
    unsigned int dh = (unsigned int)__half_as_ushort(__float2half_rn(dv));
    w[3] = (unsigned int)n24 | ((unsigned int)n25 << 4) | ((unsigned int)n26 << 8)
         | ((unsigned int)e << 12) | (dh << 16);
    lo = make_uint4(w[0], w[1], w[2], w[3]);
    (void)hi;
}

// ---------------------------------------------------------------------------
// Pack (C,D,H,W) fp32 -> 16 B voxels, ONE FULL BRICK PER THREAD.
// The 4 x-pair iterations of a thread write the 4 quarters of the same
// 128 B line back-to-back -> L2 write-combines to full-line writes.
// Reads stay fully coalesced (lanes = adjacent bx -> contiguous x).
// ---------------------------------------------------------------------------
__global__ __launch_bounds__(256) void pack_kernel(
    const float* __restrict__ dens,
    const float* __restrict__ sh,
    uint4* __restrict__ vol,
    int V)
{
    int b = blockIdx.x * blockDim.x + threadIdx.x;
    int nb = V >> 3;
    if (b >= nb) return;

    int bx = b & (GB - 1);
    int by = (b >> 6) & (GB - 1);
    int bz = b >> 12;
    int x0 = bx << 1, y0 = by << 1, z0 = bz << 1;

#pragma unroll
    for (int dz = 0; dz < 2; ++dz) {
#pragma unroll
        for (int dy = 0; dy < 2; ++dy) {
            int v0 = (((z0 + dz) * GR) + (y0 + dy)) * GR + x0;

            float2 dd = *reinterpret_cast<const float2*>(dens + v0);
            float sa[27], sb[27];
#pragma unroll
            for (int q = 0; q < 27; ++q) {
                float2 s2 = *reinterpret_cast<const float2*>(
                    sh + (size_t)q * (size_t)V + v0);
                sa[q] = s2.x;
                sb[q] = s2.y;
            }

            uint4 ea, eb, dummy;
            enc_voxel(sa, dd.x, ea, dummy);
            enc_voxel(sb, dd.y, eb, dummy);

            int slot = b * 8 + (dz << 2) + (dy << 1);
            vol[slot + 0] = ea;
            vol[slot + 1] = eb;
        }
    }
}

// ---------------------------------------------------------------------------
// Shade 8 fetched corners -> {density, r, g, b}  (R8-proven math).
// ---------------------------------------------------------------------------
__device__ __forceinline__ fvec4 shade_eval(
    uint4 c000, uint4 c001, uint4 c010, uint4 c011,
    uint4 c100, uint4 c101, uint4 c110, uint4 c111,
    float wx1, float wy1, float wz1,
    float dxv, float dyv, float dzv)
{
    float wx0 = 1.0f - wx1, wy0 = 1.0f - wy1, wz0 = 1.0f - wz1;
    float w000 = wz0 * wy0 * wx0, w001 = wz0 * wy0 * wx1;
    float w010 = wz0 * wy1 * wx0, w011 = wz0 * wy1 * wx1;
    float w100 = wz1 * wy0 * wx0, w101 = wz1 * wy0 * wx1;
    float w110 = wz1 * wy1 * wx0, w111 = wz1 * wy1 * wx1;

    __half2 acc2[15];
#pragma unroll
    for (int p = 0; p < 15; ++p) acc2[p] = u2h2(0u);
    float G = 0.0f, accd = 0.0f;

    #define NIB4(DW, O)                                                        \
    {                                                                          \
        acc2[(O)+0] = __hfma2(g2, u2h2((((DW) << 6) & 0x03C003C0u) | 0x3C003C00u), acc2[(O)+0]); \
        acc2[(O)+1] = __hfma2(g2, u2h2((((DW) << 2) & 0x03C003C0u) | 0x3C003C00u), acc2[(O)+1]); \
        acc2[(O)+2] = __hfma2(g2, u2h2((((DW) >> 2) & 0x03C003C0u) | 0x3C003C00u), acc2[(O)+2]); \
        acc2[(O)+3] = __hfma2(g2, u2h2((((DW) >> 6) & 0x03C003C0u) | 0x3C003C00u), acc2[(O)+3]); \
    }
    #define NIB3(DW, O)                                                        \
    {                                                                          \
        acc2[(O)+0] = __hfma2(g2, u2h2((((DW) << 6) & 0x03C003C0u) | 0x3C003C00u), acc2[(O)+0]); \
        acc2[(O)+1] = __hfma2(g2, u2h2((((DW) << 2) & 0x03C003C0u) | 0x3C003C00u), acc2[(O)+1]); \
        acc2[(O)+2] = __hfma2(g2, u2h2((((DW) >> 2) & 0x03C003C0u) | 0x3C003C00u), acc2[(O)+2]); \
    }
    #define CORNER(C, W)                                                       \
    {                                                                          \
        float w_ = (W);                                                        \
        unsigned int e_ = ((C).w >> 12) & 0xFu;                                \
        float f_ = __uint_as_float((113u + e_) << 23);   /* 2^(e-14) */        \
        float g_ = w_ * f_;                                                    \
        G += g_;                                                               \
        accd = fmaf(w_, __half2float(__ushort_as_half((unsigned short)((C).w >> 16))), accd); \
        __half2 g2 = __float2half2_rn(g_);                                     \
        NIB4((C).x, 0) NIB4((C).y, 4) NIB4((C).z, 8) NIB3((C).w, 12)           \
    }

    CORNER(c000, w000) CORNER(c001, w001) CORNER(c010, w010) CORNER(c011, w011)
    CORNER(c100, w100) CORNER(c101, w101) CORNER(c110, w110) CORNER(c111, w111)
    #undef CORNER
    #undef NIB4
    #undef NIB3

    float c24G = 24.0f * G;
    float sch[27];
#pragma unroll
    for (int d = 0; d < 3; ++d) {
#pragma unroll
        for (int p = 0; p < 4; ++p) {
            float2 f2 = __half22float2(acc2[d * 4 + p]);
            sch[8 * d + p]     = fmaf(16.0f, f2.x, -c24G);
            sch[8 * d + p + 4] = fmaf(16.0f, f2.y, -c24G);
        }
    }
#pragma unroll
    for (int p = 0; p < 3; ++p) {
        float2 f2 = __half22float2(acc2[12 + p]);
        sch[24 + p] = fmaf(16.0f, f2.x, -c24G);
    }

    float xx = dxv*dxv, yy = dyv*dyv, zz = dzv*dzv;
    float bs[9];
    bs[0] = 0.28209479177387814f;
    bs[1] = -0.4886025119029199f * dyv;
    bs[2] =  0.4886025119029199f * dzv;
    bs[3] = -0.4886025119029199f * dxv;
    bs[4] =  1.0925484305920792f * dxv * dyv;
    bs[5] = -1.0925484305920792f * dyv * dzv;
    bs[6] =  0.31539156525252005f * (2.0f*zz - xx - yy);
    bs[7] = -1.0925484305920792f * dxv * dzv;
    bs[8] =  0.5462742152960396f * (xx - yy);

    fvec4 res;
    res.x = fmaxf(accd, 0.0f);
#pragma unroll
    for (int ch = 0; ch < 3; ++ch) {
        float sm = 0.0f;
#pragma unroll
        for (int q = 0; q < 9; ++q) sm = fmaf(sch[ch*9 + q], bs[q], sm);
        if (ch == 0) res.y = sigmoidf_(sm);
        else if (ch == 1) res.z = sigmoidf_(sm);
        else res.w = sigmoidf_(sm);
    }
    return res;
}

// ---------------------------------------------------------------------------
// Main: unsorted sample of brick-ordered volume (R15-proven). Streaming
// inputs/outputs nontemporal so L2 stays reserved for volume lines.
// ---------------------------------------------------------------------------
__global__ __launch_bounds__(256) void sample_kernel(
    const float* __restrict__ xyz,
    const float* __restrict__ vdirs,
    const uint4* __restrict__ vol,
    float* __restrict__ out,
    int N)
{
    int i = blockIdx.x * blockDim.x + threadIdx.x;
    if (i >= N) return;

    float px = __builtin_nontemporal_load(xyz + 3*i + 0);
    float py = __builtin_nontemporal_load(xyz + 3*i + 1);
    float pz = __builtin_nontemporal_load(xyz + 3*i + 2);

    const float kk = (1.0f / 1.5f) * 0.5f * (float)(GR - 1);
    const float cc = 0.5f * (float)(GR - 1);
    float fx = fminf(fmaxf(fmaf(px, kk, cc), 0.0f), (float)(GR - 1));
    float fy = fminf(fmaxf(fmaf(py, kk, cc), 0.0f), (float)(GR - 1));
    float fz = fminf(fmaxf(fmaf(pz, kk, cc), 0.0f), (float)(GR - 1));
    int x0 = (int)fx, y0 = (int)fy, z0 = (int)fz;
    float wx1 = fx - (float)x0, wy1 = fy - (float)y0, wz1 = fz - (float)z0;
    int x1 = min(x0 + 1, GR - 1);
    int y1 = min(y0 + 1, GR - 1);
    int z1 = min(z0 + 1, GR - 1);

    int a000 = brick_addr(x0, y0, z0);
    int a001 = brick_addr(x1, y0, z0);
    int a010 = brick_addr(x0, y1, z0);
    int a011 = brick_addr(x1, y1, z0);
    int a100 = brick_addr(x0, y0, z1);
    int a101 = brick_addr(x1, y0, z1);
    int a110 = brick_addr(x0, y1, z1);
    int a111 = brick_addr(x1, y1, z1);

    uint4 c000 = vol[a000];
    uint4 c001 = vol[a001];
    uint4 c010 = vol[a010];
    uint4 c011 = vol[a011];
    uint4 c100 = vol[a100];
    uint4 c101 = vol[a101];
    uint4 c110 = vol[a110];
    uint4 c111 = vol[a111];

    float dxv = __builtin_nontemporal_load(vdirs + 3*i + 0);
    float dyv = __builtin_nontemporal_load(vdirs + 3*i + 1);
    float dzv = __builtin_nontemporal_load(vdirs + 3*i + 2);

    fvec4 res = shade_eval(c000, c001, c010, c011, c100, c101, c110, c111,
                           wx1, wy1, wz1, dxv, dyv, dzv);

    __builtin_nontemporal_store(res.x, &out[i]);
    size_t o = (size_t)N + 3*(size_t)i;
    __builtin_nontemporal_store(res.y, &out[o + 0]);
    __builtin_nontemporal_store(res.z, &out[o + 1]);
    __builtin_nontemporal_store(res.w, &out[o + 2]);
}

// ---------------------------------------------------------------------------
// Tiny-ws fallback: direct fp32 channel-major sampling.
// ---------------------------------------------------------------------------
__global__ __launch_bounds__(256) void sample_direct_kernel(
    const float* __restrict__ xyz,
    const float* __restrict__ vdirs,
    const float* __restrict__ dens,
    const float* __restrict__ sh,
    float* __restrict__ out,
    int N)
{
    int i = blockIdx.x * blockDim.x + threadIdx.x;
    if (i >= N) return;

    const float kk = (1.0f / 1.5f) * 0.5f * (float)(GR - 1);
    const float cc = 0.5f * (float)(GR - 1);
    float fx = fminf(fmaxf(fmaf(xyz[3*i+0], kk, cc), 0.0f), (float)(GR - 1));
    float fy = fminf(fmaxf(fmaf(xyz[3*i+1], kk, cc), 0.0f), (float)(GR - 1));
    float fz = fminf(fmaxf(fmaf(xyz[3*i+2], kk, cc), 0.0f), (float)(GR - 1));
    float x0f = floorf(fx), y0f = floorf(fy), z0f = floorf(fz);
    float wx1 = fx - x0f, wy1 = fy - y0f, wz1 = fz - z0f;
    int x0 = (int)x0f, y0 = (int)y0f, z0 = (int)z0f;
    float wx[2] = { 1.0f - wx1, wx1 };
    float wy[2] = { 1.0f - wy1, wy1 };
    float wz[2] = { 1.0f - wz1, wz1 };
    int xi[2] = { x0, min(x0 + 1, GR-1) };
    int yi[2] = { y0, min(y0 + 1, GR-1) };
    int zi[2] = { z0, min(z0 + 1, GR-1) };

    const size_t V = (size_t)GR * GR * GR;
    float acc[NCH];
#pragma unroll
    for (int c = 0; c < NCH; ++c) acc[c] = 0.0f;

#pragma unroll
    for (int dz = 0; dz < 2; ++dz)
#pragma unroll
        for (int dy = 0; dy < 2; ++dy)
#pragma unroll
            for (int dx = 0; dx < 2; ++dx) {
                float w = wz[dz] * wy[dy] * wx[dx];
                size_t vox = (((size_t)zi[dz] * GR) + yi[dy]) * GR + xi[dx];
                acc[0] = fmaf(w, dens[vox], acc[0]);
#pragma unroll
                for (int c = 0; c < 27; ++c)
                    acc[1 + c] = fmaf(w, sh[(size_t)c * V + vox], acc[1 + c]);
            }

    float dxv = vdirs[3*i+0], dyv = vdirs[3*i+1], dzv = vdirs[3*i+2];
    float xx = dxv*dxv, yy = dyv*dyv, zz = dzv*dzv;
    float b[9];
    b[0] = 0.28209479177387814f;
    b[1] = -0.4886025119029199f * dyv;
    b[2] =  0.4886025119029199f * dzv;
    b[3] = -0.4886025119029199f * dxv;
    b[4] =  1.0925484305920792f * dxv * dyv;
    b[5] = -1.0925484305920792f * dyv * dzv;
    b[6] =  0.31539156525252005f * (2.0f*zz - xx - yy);
    b[7] = -1.0925484305920792f * dxv * dzv;
    b[8] =  0.5462742152960396f * (xx - yy);

    out[i] = fmaxf(acc[0], 0.0f);
#pragma unroll
    for (int c = 0; c < 3; ++c) {
        float sm = 0.0f;
#pragma unroll
        for (int q = 0; q < 9; ++q) sm = fmaf(acc[1 + c*9 + q], b[q], sm);
        out[(size_t)N + 3*(size_t)i + c] = sigmoidf_(sm);
    }
}

extern "C" void kernel_launch(void* const* d_in, const int* in_sizes, int n_in,
                              void* d_out, int out_size, void* d_ws, size_t ws_size,
                              hipStream_t stream) {
    const float* xyz   = (const float*)d_in[0];
    const float* vdirs = (const float*)d_in[1];
    const float* dens  = (const float*)d_in[2];
    const float* sh    = (const float*)d_in[3];
    float* out = (float*)d_out;

    int N = in_sizes[0] / 3;
    const int V = GR * GR * GR;
    size_t need = (size_t)V * 16;        // 33.5 MB packed volume

    if (ws_size >= need) {
        uint4* vol = (uint4*)d_ws;
        int nb = V >> 3;                 // one thread per 2x2x2 brick
        pack_kernel<<<(nb + 255) / 256, 256, 0, stream>>>(dens, sh, vol, V);
        sample_kernel<<<(N + 255) / 256, 256, 0, stream>>>(xyz, vdirs, vol, out, N);
    } else {
        sample_direct_kernel<<<(N + 255) / 256, 256, 0, stream>>>(xyz, vdirs, dens, sh, out, N);
    }
}

// Round 17
// 171.844 us; speedup vs baseline: 1.0525x; 1.0525x over previous
//
#include <hip/hip_runtime.h>
#include <hip/hip_fp16.h>
#include <math.h>

#define GR 128            // grid resolution
#define GB 64             // bricks per axis (2x2x2-voxel bricks)
#define NCH 28            // real channels (1 density + 27 SH)

typedef float fvec4 __attribute__((ext_vector_type(4)));

// ---------------------------------------------------------------------------
// 16-byte voxel (R8-proven), stored in 2x2x2-voxel bricks so one brick =
// 8 voxels x 16 B = exactly one 128 B cache line.
//   brick(bx,by,bz) at ((bz*GB+by)*GB+bx)*8 ; voxel offset (z&1)<<2|(y&1)<<1|(x&1)
//   dword0: SH nibbles c0..c7, dword1: c8..c15, dword2: c16..c23
//   dword3: [3:0]=c24 [7:4]=c25 [11:8]=c26 [15:12]=e, [31:16]=density fp16
// SH coef value = (n - 8) * 2^(e-14)
// ---------------------------------------------------------------------------

__device__ __forceinline__ float sigmoidf_(float x) {
    return 1.0f / (1.0f + expf(-x));
}
__device__ __forceinline__ __half2 u2h2(unsigned int u) {
    return *reinterpret_cast<__half2*>(&u);
}
__device__ __forceinline__ int brick_addr(int x, int y, int z) {
    int b = ((z >> 1) * GB + (y >> 1)) * GB + (x >> 1);
    return b * 8 + ((z & 1) << 2) + ((y & 1) << 1) + (x & 1);
}

// encode one voxel's 27 SH + density into one uint4 (R8-proven format)
__device__ __forceinline__ uint4 enc_voxel(const float* sv, float dv) {
    float mp = 0.0f, mn = 0.0f;
#pragma unroll
    for (int q = 0; q < 27; ++q) {
        float xq = sv[q];
        mp = fmaxf(mp, xq);
        mn = fmaxf(mn, -xq);
    }
    float tq = fmaxf(fmaxf(mp * (1.0f / 7.0f), mn * 0.125f), 7.5e-9f);
    int ex = (int)((__float_as_uint(tq) >> 23) & 0xFFu) - 126;
    int e = min(max(ex + 14, 0), 15);
    float invf = __uint_as_float((unsigned int)(141 - e) << 23);  // 2^(14-e)

    unsigned int w[4];
#pragma unroll
    for (int d = 0; d < 3; ++d) {
        unsigned int acc = 0;
#pragma unroll
        for (int b = 0; b < 8; ++b) {
            int n = (int)rintf(sv[8 * d + b] * invf) + 8;
            n = min(max(n, 0), 15);
            acc |= (unsigned int)n << (4 * b);
        }
        w[d] = acc;
    }
    int n24 = min(max((int)rintf(sv[24] * invf) + 8, 0), 15);
    int n25 = min(max((int)rintf(sv[25] * invf) + 8, 0), 15);
    int n26 = min(max((int)rintf(sv[26] * invf) + 8, 0), 15);
    unsigned int dh = (unsigned int)__half_as_ushort(__float2half_rn(dv));
    w[3] = (unsigned int)n24 | ((unsigned int)n25 << 4) | ((unsigned int)n26 << 8)
         | ((unsigned int)e << 12) | (dh << 16);
    return make_uint4(w[0], w[1], w[2], w[3]);
}

// ---------------------------------------------------------------------------
// LDS-tiled pack: block covers 128x4x2 voxels (= 128 bricks = 16 KB out).
// Reads: float4 per channel, quarter-wave contiguous (coalesced).
// Writes: encode -> LDS (brick order) -> cooperative store; each store
// instruction writes 64 lanes x 16 B consecutive = 8 FULL 128 B lines.
// ---------------------------------------------------------------------------
__global__ __launch_bounds__(256) void pack_kernel(
    const float* __restrict__ dens,
    const float* __restrict__ sh,
    uint4* __restrict__ vol,
    int V)
{
    __shared__ uint4 lds[1024];    // 16 KB

    int blk = blockIdx.x;          // 2048 blocks: 64 z-pairs x 32 y-quads
    int zp = blk >> 5;             // 0..63
    int yq = blk & 31;             // 0..31
    int z0 = zp << 1;
    int y0 = yq << 2;

    int t = (int)threadIdx.x;
    int row = t >> 5;              // 0..7
    int dy = row & 3, dz = row >> 2;
    int xq = (t & 31) << 2;        // 0,4,...,124

    int y = y0 + dy, z = z0 + dz;
    size_t v0 = ((size_t)z * GR + y) * GR + xq;

    float4 dd = *reinterpret_cast<const float4*>(dens + v0);
    float s[4][27];
#pragma unroll
    for (int q = 0; q < 27; ++q) {
        float4 sv = *reinterpret_cast<const float4*>(sh + (size_t)q * (size_t)V + v0);
        s[0][q] = sv.x; s[1][q] = sv.y; s[2][q] = sv.z; s[3][q] = sv.w;
    }

#pragma unroll
    for (int j = 0; j < 4; ++j) {
        float dv = (j == 0) ? dd.x : (j == 1) ? dd.y : (j == 2) ? dd.z : dd.w;
        uint4 enc = enc_voxel(s[j], dv);
        int xx = xq + j;
        int lb = ((dy >> 1) << 6) | (xx >> 1);                  // 0..127
        int slot = (dz << 2) | ((dy & 1) << 1) | (xx & 1);      // 0..7
        lds[lb * 8 + slot] = enc;
    }
    __syncthreads();

    int bz0 = z0 >> 1;
    int by0 = yq << 1;
#pragma unroll
    for (int k = 0; k < 4; ++k) {
        int l = t + k * 256;
        int lby = l >> 9;
        size_t g = (((size_t)bz0 * GB + (size_t)(by0 + lby)) * GB) * 8 + (size_t)(l & 511);
        vol[g] = lds[l];
    }
}

// ---------------------------------------------------------------------------
// Shade 8 fetched corners -> {density, r, g, b}  (R8-proven math).
// ---------------------------------------------------------------------------
__device__ __forceinline__ fvec4 shade_eval(
    uint4 c000, uint4 c001, uint4 c010, uint4 c011,
    uint4 c100, uint4 c101, uint4 c110, uint4 c111,
    float wx1, float wy1, float wz1,
    float dxv, float dyv, float dzv)
{
    float wx0 = 1.0f - wx1, wy0 = 1.0f - wy1, wz0 = 1.0f - wz1;
    float w000 = wz0 * wy0 * wx0, w001 = wz0 * wy0 * wx1;
    float w010 = wz0 * wy1 * wx0, w011 = wz0 * wy1 * wx1;
    float w100 = wz1 * wy0 * wx0, w101 = wz1 * wy0 * wx1;
    float w110 = wz1 * wy1 * wx0, w111 = wz1 * wy1 * wx1;

    __half2 acc2[15];
#pragma unroll
    for (int p = 0; p < 15; ++p) acc2[p] = u2h2(0u);
    float G = 0.0f, accd = 0.0f;

    #define NIB4(DW, O)                                                        \
    {                                                                          \
        acc2[(O)+0] = __hfma2(g2, u2h2((((DW) << 6) & 0x03C003C0u) | 0x3C003C00u), acc2[(O)+0]); \
        acc2[(O)+1] = __hfma2(g2, u2h2((((DW) << 2) & 0x03C003C0u) | 0x3C003C00u), acc2[(O)+1]); \
        acc2[(O)+2] = __hfma2(g2, u2h2((((DW) >> 2) & 0x03C003C0u) | 0x3C003C00u), acc2[(O)+2]); \
        acc2[(O)+3] = __hfma2(g2, u2h2((((DW) >> 6) & 0x03C003C0u) | 0x3C003C00u), acc2[(O)+3]); \
    }
    #define NIB3(DW, O)                                                        \
    {                                                                          \
        acc2[(O)+0] = __hfma2(g2, u2h2((((DW) << 6) & 0x03C003C0u) | 0x3C003C00u), acc2[(O)+0]); \
        acc2[(O)+1] = __hfma2(g2, u2h2((((DW) << 2) & 0x03C003C0u) | 0x3C003C00u), acc2[(O)+1]); \
        acc2[(O)+2] = __hfma2(g2, u2h2((((DW) >> 2) & 0x03C003C0u) | 0x3C003C00u), acc2[(O)+2]); \
    }
    #define CORNER(C, W)                                                       \
    {                                                                          \
        float w_ = (W);                                                        \
        unsigned int e_ = ((C).w >> 12) & 0xFu;                                \
        float f_ = __uint_as_float((113u + e_) << 23);   /* 2^(e-14) */        \
        float g_ = w_ * f_;                                                    \
        G += g_;                                                               \
        accd = fmaf(w_, __half2float(__ushort_as_half((unsigned short)((C).w >> 16))), accd); \
        __half2 g2 = __float2half2_rn(g_);                                     \
        NIB4((C).x, 0) NIB4((C).y, 4) NIB4((C).z, 8) NIB3((C).w, 12)           \
    }

    CORNER(c000, w000) CORNER(c001, w001) CORNER(c010, w010) CORNER(c011, w011)
    CORNER(c100, w100) CORNER(c101, w101) CORNER(c110, w110) CORNER(c111, w111)
    #undef CORNER
    #undef NIB4
    #undef NIB3

    float c24G = 24.0f * G;
    float sch[27];
#pragma unroll
    for (int d = 0; d < 3; ++d) {
#pragma unroll
        for (int p = 0; p < 4; ++p) {
            float2 f2 = __half22float2(acc2[d * 4 + p]);
            sch[8 * d + p]     = fmaf(16.0f, f2.x, -c24G);
            sch[8 * d + p + 4] = fmaf(16.0f, f2.y, -c24G);
        }
    }
#pragma unroll
    for (int p = 0; p < 3; ++p) {
        float2 f2 = __half22float2(acc2[12 + p]);
        sch[24 + p] = fmaf(16.0f, f2.x, -c24G);
    }

    float xx = dxv*dxv, yy = dyv*dyv, zz = dzv*dzv;
    float bs[9];
    bs[0] = 0.28209479177387814f;
    bs[1] = -0.4886025119029199f * dyv;
    bs[2] =  0.4886025119029199f * dzv;
    bs[3] = -0.4886025119029199f * dxv;
    bs[4] =  1.0925484305920792f * dxv * dyv;
    bs[5] = -1.0925484305920792f * dyv * dzv;
    bs[6] =  0.31539156525252005f * (2.0f*zz - xx - yy);
    bs[7] = -1.0925484305920792f * dxv * dzv;
    bs[8] =  0.5462742152960396f * (xx - yy);

    fvec4 res;
    res.x = fmaxf(accd, 0.0f);
#pragma unroll
    for (int ch = 0; ch < 3; ++ch) {
        float sm = 0.0f;
#pragma unroll
        for (int q = 0; q < 9; ++q) sm = fmaf(sch[ch*9 + q], bs[q], sm);
        if (ch == 0) res.y = sigmoidf_(sm);
        else if (ch == 1) res.z = sigmoidf_(sm);
        else res.w = sigmoidf_(sm);
    }
    return res;
}

// ---------------------------------------------------------------------------
// Main: unsorted sample of brick-ordered volume (R15-proven, unchanged).
// ---------------------------------------------------------------------------
__global__ __launch_bounds__(256) void sample_kernel(
    const float* __restrict__ xyz,
    const float* __restrict__ vdirs,
    const uint4* __restrict__ vol,
    float* __restrict__ out,
    int N)
{
    int i = blockIdx.x * blockDim.x + threadIdx.x;
    if (i >= N) return;

    float px = __builtin_nontemporal_load(xyz + 3*i + 0);
    float py = __builtin_nontemporal_load(xyz + 3*i + 1);
    float pz = __builtin_nontemporal_load(xyz + 3*i + 2);

    const float kk = (1.0f / 1.5f) * 0.5f * (float)(GR - 1);
    const float cc = 0.5f * (float)(GR - 1);
    float fx = fminf(fmaxf(fmaf(px, kk, cc), 0.0f), (float)(GR - 1));
    float fy = fminf(fmaxf(fmaf(py, kk, cc), 0.0f), (float)(GR - 1));
    float fz = fminf(fmaxf(fmaf(pz, kk, cc), 0.0f), (float)(GR - 1));
    int x0 = (int)fx, y0 = (int)fy, z0 = (int)fz;
    float wx1 = fx - (float)x0, wy1 = fy - (float)y0, wz1 = fz - (float)z0;
    int x1 = min(x0 + 1, GR - 1);
    int y1 = min(y0 + 1, GR - 1);
    int z1 = min(z0 + 1, GR - 1);

    int a000 = brick_addr(x0, y0, z0);
    int a001 = brick_addr(x1, y0, z0);
    int a010 = brick_addr(x0, y1, z0);
    int a011 = brick_addr(x1, y1, z0);
    int a100 = brick_addr(x0, y0, z1);
    int a101 = brick_addr(x1, y0, z1);
    int a110 = brick_addr(x0, y1, z1);
    int a111 = brick_addr(x1, y1, z1);

    uint4 c000 = vol[a000];
    uint4 c001 = vol[a001];
    uint4 c010 = vol[a010];
    uint4 c011 = vol[a011];
    uint4 c100 = vol[a100];
    uint4 c101 = vol[a101];
    uint4 c110 = vol[a110];
    uint4 c111 = vol[a111];

    float dxv = __builtin_nontemporal_load(vdirs + 3*i + 0);
    float dyv = __builtin_nontemporal_load(vdirs + 3*i + 1);
    float dzv = __builtin_nontemporal_load(vdirs + 3*i + 2);

    fvec4 res = shade_eval(c000, c001, c010, c011, c100, c101, c110, c111,
                           wx1, wy1, wz1, dxv, dyv, dzv);

    __builtin_nontemporal_store(res.x, &out[i]);
    size_t o = (size_t)N + 3*(size_t)i;
    __builtin_nontemporal_store(res.y, &out[o + 0]);
    __builtin_nontemporal_store(res.z, &out[o + 1]);
    __builtin_nontemporal_store(res.w, &out[o + 2]);
}

// ---------------------------------------------------------------------------
// Tiny-ws fallback: direct fp32 channel-major sampling.
// ---------------------------------------------------------------------------
__global__ __launch_bounds__(256) void sample_direct_kernel(
    const float* __restrict__ xyz,
    const float* __restrict__ vdirs,
    const float* __restrict__ dens,
    const float* __restrict__ sh,
    float* __restrict__ out,
    int N)
{
    int i = blockIdx.x * blockDim.x + threadIdx.x;
    if (i >= N) return;

    const float kk = (1.0f / 1.5f) * 0.5f * (float)(GR - 1);
    const float cc = 0.5f * (float)(GR - 1);
    float fx = fminf(fmaxf(fmaf(xyz[3*i+0], kk, cc), 0.0f), (float)(GR - 1));
    float fy = fminf(fmaxf(fmaf(xyz[3*i+1], kk, cc), 0.0f), (float)(GR - 1));
    float fz = fminf(fmaxf(fmaf(xyz[3*i+2], kk, cc), 0.0f), (float)(GR - 1));
    float x0f = floorf(fx), y0f = floorf(fy), z0f = floorf(fz);
    float wx1 = fx - x0f, wy1 = fy - y0f, wz1 = fz - z0f;
    int x0 = (int)x0f, y0 = (int)y0f, z0 = (int)z0f;
    float wx[2] = { 1.0f - wx1, wx1 };
    float wy[2] = { 1.0f - wy1, wy1 };
    float wz[2] = { 1.0f - wz1, wz1 };
    int xi[2] = { x0, min(x0 + 1, GR-1) };
    int yi[2] = { y0, min(y0 + 1, GR-1) };
    int zi[2] = { z0, min(z0 + 1, GR-1) };

    const size_t V = (size_t)GR * GR * GR;
    float acc[NCH];
#pragma unroll
    for (int c = 0; c < NCH; ++c) acc[c] = 0.0f;

#pragma unroll
    for (int dz = 0; dz < 2; ++dz)
#pragma unroll
        for (int dy = 0; dy < 2; ++dy)
#pragma unroll
            for (int dx = 0; dx < 2; ++dx) {
                float w = wz[dz] * wy[dy] * wx[dx];
                size_t vox = (((size_t)zi[dz] * GR) + yi[dy]) * GR + xi[dx];
                acc[0] = fmaf(w, dens[vox], acc[0]);
#pragma unroll
                for (int c = 0; c < 27; ++c)
                    acc[1 + c] = fmaf(w, sh[(size_t)c * V + vox], acc[1 + c]);
            }

    float dxv = vdirs[3*i+0], dyv = vdirs[3*i+1], dzv = vdirs[3*i+2];
    float xx = dxv*dxv, yy = dyv*dyv, zz = dzv*dzv;
    float b[9];
    b[0] = 0.28209479177387814f;
    b[1] = -0.4886025119029199f * dyv;
    b[2] =  0.4886025119029199f * dzv;
    b[3] = -0.4886025119029199f * dxv;
    b[4] =  1.0925484305920792f * dxv * dyv;
    b[5] = -1.0925484305920792f * dyv * dzv;
    b[6] =  0.31539156525252005f * (2.0f*zz - xx - yy);
    b[7] = -1.0925484305920792f * dxv * dzv;
    b[8] =  0.5462742152960396f * (xx - yy);

    out[i] = fmaxf(acc[0], 0.0f);
#pragma unroll
    for (int c = 0; c < 3; ++c) {
        float sm = 0.0f;
#pragma unroll
        for (int q = 0; q < 9; ++q) sm = fmaf(acc[1 + c*9 + q], b[q], sm);
        out[(size_t)N + 3*(size_t)i + c] = sigmoidf_(sm);
    }
}

extern "C" void kernel_launch(void* const* d_in, const int* in_sizes, int n_in,
                              void* d_out, int out_size, void* d_ws, size_t ws_size,
                              hipStream_t stream) {
    const float* xyz   = (const float*)d_in[0];
    const float* vdirs = (const float*)d_in[1];
    const float* dens  = (const float*)d_in[2];
    const float* sh    = (const float*)d_in[3];
    float* out = (float*)d_out;

    int N = in_sizes[0] / 3;
    const int V = GR * GR * GR;
    size_t need = (size_t)V * 16;        // 33.5 MB packed volume

    if (ws_size >= need) {
        uint4* vol = (uint4*)d_ws;
        // 2048 blocks: 64 z-pairs x 32 y-quads, 128x4x2 voxels each
        pack_kernel<<<2048, 256, 0, stream>>>(dens, sh, vol, V);
        sample_kernel<<<(N + 255) / 256, 256, 0, stream>>>(xyz, vdirs, vol, out, N);
    } else {
        sample_direct_kernel<<<(N + 255) / 256, 256, 0, stream>>>(xyz, vdirs, dens, sh, out, N);
    }
}